// Round 3
// baseline (213.219 us; speedup 1.0000x reference)
//
#include <hip/hip_runtime.h>

// SPGG Q-learning step on a 2048x2048 torus — SINGLE fused kernel, v4.
//
// v3 post-mortem (70.5 us): time saved tracks VALU-cycles saved 1:1 across
// v1->v2->v3 while no pipe exceeds ~31% -> the kernel is serial-chain /
// barrier-convoy bound, not throughput bound. v4 attacks the serial path:
//
//  1. 4 cells/thread (4x256 strip per block): halo rows per compute-row
//     4 -> 2.5, b-values per cell 3.05 -> 2.05, barriers per cell halved,
//     4 independent tail chains (f64 exp latencies interleave 4-deep).
//  2. tt staging via __builtin_amdgcn_global_load_lds width=16: no VGPR
//     round-trip, no ds_write_b128 (VALU+LDS work removed from the hottest
//     phase), shorter phase-1 drain. LDS dest is linear in lane id (the
//     required wave-uniform-base + lane*16 pattern). Staging is padded to
//     3 full iterations (768 int4 >= 660 needed); stray writes land in the
//     btile region of a manually-overlaid LDS block and are fully
//     overwritten in phase 2 before any read.
//  3. Neighbor Q/tmin gathers issue at the TOP of phase 3 (after the last
//     barrier) instead of pre-barrier: in v3 the ldir->nidx->gather chain
//     was drained by barrier 1 (~2 dependent HBM round-trips on the phase-1
//     critical path). Now the barrier drains at staging-complete and the
//     gathers overlap own-profit compute, waited only at first use.
//
// Numerics: identical per-cell op sequence as the passing v1-v3 (int-exact
// coop sums; __f*_rn ops in the reference's exact order; exp in double,
// rounded once).

#define LSIDE 2048
#define LMASK 2047
#define LSHIFT 11
#define NCELL (LSIDE * LSIDE)

#define CROWS 4     // cell rows per block (1 per thread, vertical)
#define TROWS 10    // tt rows i0-3 .. i0+6
#define TCOLS 264   // 256 + 2*4 halo (4-aligned); 264*4B row = 16B-aligned
#define TI4   66    // int4s per tile row
#define NI4   (TROWS * TI4)          // 660 int4s actually needed
#define BROWS 8     // b rows i0-2 .. i0+5
#define BCOLS 260   // b cols j0-2 .. j0+257
#define TILE_INTS (TROWS * TCOLS)            // 2640
#define LDS_INTS  (TILE_INTS + BROWS * BCOLS) // 4720 ints = 18880 B

typedef __attribute__((address_space(1))) const int gas_int;
typedef __attribute__((address_space(3))) int las_int;

__global__ __launch_bounds__(256) void spgg_fused(
    const int* __restrict__ tmin,   // type_t_minus
    const int* __restrict__ tt,     // type_t
    const float* __restrict__ Q,    // Q_tensor [N,4]
    const int* __restrict__ ldir,   // learning_direction
    const float* __restrict__ lp,   // learning_probabilities
    float* __restrict__ Qn,         // out: Q_new [N,4]
    float* __restrict__ prof,       // out: profit [N]
    float* __restrict__ t1out)      // out: type_t1 [N]
{
    __shared__ __align__(16) int lds_raw[LDS_INTS];
    int   (*tile)[TCOLS]  = reinterpret_cast<int(*)[TCOLS]>(lds_raw);
    float (*btile)[BCOLS] = reinterpret_cast<float(*)[BCOLS]>(lds_raw + TILE_INTS);

    const int t   = threadIdx.x;
    const int blk = blockIdx.x;
    const int i0  = (blk >> 3) << 2;     // 4 lattice rows per block
    const int j0  = (blk & 7) << 8;      // 256 cells per block-row
    const int j   = j0 + t;
    const int idx0 = (i0 << LSHIFT) + j;

    // ---- phase 1: early per-cell loads (independent, drain at barrier 1) ----
    int    dirm[CROWS];
    float  pvm[CROWS];
    float4 qrm[CROWS];
    int    Am[CROWS];
    #pragma unroll
    for (int m = 0; m < CROWS; ++m) {
        int idx = idx0 + (m << LSHIFT);
        dirm[m] = ldir[idx];
        pvm[m]  = lp[idx];
        qrm[m]  = ((const float4*)Q)[idx];
        Am[m]   = tmin[idx];
    }

    // ---- tt staging: direct global->LDS DMA, 3 tail-free iterations ----
    // k in [0,768): k >= NI4(660) writes land in the btile overlay region
    // (byte 10560..12287 < 18880) and are rewritten in phase 2 before reads.
    #pragma unroll
    for (int it = 0; it < 3; ++it) {
        int k = t + (it << 8);
        int r = k / TI4;                           // 0..11 (rows 10,11 stray)
        int m4 = k - r * TI4;
        int row_g = (i0 + r - 3) & LMASK;
        int col_g = (j0 - 4 + (m4 << 2)) & LMASK;  // multiple of 4 -> aligned
        __builtin_amdgcn_global_load_lds(
            (gas_int*)&tt[(row_g << LSHIFT) + col_g],
            (las_int*)&lds_raw[k << 2], 16, 0, 0);
    }

    __syncthreads();

    const float KB        = 0.5554f;  // float32(R / 5.0)
    const float ETA       = 0.8f;
    const float ONE_M_ETA = 0.2f;     // float32(1.0 - 0.8)
    const float GAMMA     = 0.8f;

    // ---- phase 2: b-precompute, one coop_num*KB per cell ----
    // btile[r][c] <-> global cell (i0-2+r, j0-2+c) <-> tile coords (r+1, c+2).
    // tt values are {0,1} so the cooperator mask IS the value; int-add order
    // is exact; the single __fmul_rn is the reference's op.
    auto bval = [&](int tr, int tc) -> float {
        int cn = tile[tr][tc] + tile[tr-1][tc] + tile[tr+1][tc]
               + tile[tr][tc-1] + tile[tr][tc+1];
        return __fmul_rn((float)cn, KB);
    };
    #pragma unroll
    for (int r = 0; r < BROWS; ++r)
        btile[r][t] = bval(r + 1, t + 2);
    if (t < BCOLS - 256) {              // 4 leftover columns
        #pragma unroll
        for (int r = 0; r < BROWS; ++r)
            btile[r][256 + t] = bval(r + 1, 258 + t);
    }
    __syncthreads();   // vmcnt already 0 here -> cheap (lgkm only)

    // ---- phase 3: gathers first (overlap compute), then 4 cell chains ----
    int di[CROWS], dj[CROWS];
    float4 qn4[CROWS];
    int    An[CROWS];
    #pragma unroll
    for (int m = 0; m < CROWS; ++m) {
        // dir: 0=left(j-1) 1=right(j+1) 2=up(i-1) 3=down(i+1)
        di[m] = (dirm[m] == 3) - (dirm[m] == 2);
        dj[m] = (dirm[m] == 1) - (dirm[m] == 0);
        int nidx = ((((i0 + m + di[m]) & LMASK)) << LSHIFT) + ((j + dj[m]) & LMASK);
        qn4[m] = ((const float4*)Q)[nidx];
        An[m]  = tmin[nidx];
    }

    // profit at btile coords (r,c) — reference's exact op order:
    // plus_sum order (c, i-1, i+1, j-1, j+1); s1 subtracts 1.0 per term.
    auto profit_from_b = [&](int r, int c, int coop) -> float {
        float b_c = btile[r][c];
        float b_u = btile[r-1][c];
        float b_d = btile[r+1][c];
        float b_l = btile[r][c-1];
        float b_r = btile[r][c+1];
        float s0 = __fadd_rn(__fadd_rn(__fadd_rn(__fadd_rn(b_c, b_u), b_d), b_l), b_r);
        float s1 = __fadd_rn(__fadd_rn(__fadd_rn(__fadd_rn(
                       __fsub_rn(b_c, 1.0f), __fsub_rn(b_u, 1.0f)),
                       __fsub_rn(b_d, 1.0f)), __fsub_rn(b_l, 1.0f)),
                       __fsub_rn(b_r, 1.0f));
        return coop ? s1 : s0;
    };

    // Q-learning update value — exact reference op order.
    auto upd_of = [&](float profit, float4 q4, int Ai, int Bi) -> float {
        float q0 = (Bi == 0) ? q4.x : q4.z;
        float q1 = (Bi == 0) ? q4.y : q4.w;
        float mx = fmaxf(q0, q1);
        int k = Ai * 2 + Bi;
        float old = (k == 0) ? q4.x : ((k == 1) ? q4.y : ((k == 2) ? q4.z : q4.w));
        float t0 = __fmul_rn(GAMMA, mx);
        float t1 = __fadd_rn(profit, t0);
        float t2 = __fmul_rn(ETA, t1);
        float t3 = __fmul_rn(ONE_M_ETA, old);
        return __fadd_rn(t3, t2);
    };

    // own-cell profits + Q updates (4 independent chains)
    int   B[CROWS];
    float updv[CROWS];
    #pragma unroll
    for (int m = 0; m < CROWS; ++m) {
        B[m] = tile[m + 3][t + 4];
        float p_own = profit_from_b(m + 2, t + 2, B[m]);
        updv[m] = upd_of(p_own, qrm[m], Am[m], B[m]);
        int idx = idx0 + (m << LSHIFT);
        int k = Am[m] * 2 + B[m];
        float4 qo;
        qo.x = (k == 0) ? updv[m] : qrm[m].x;
        qo.y = (k == 1) ? updv[m] : qrm[m].y;
        qo.z = (k == 2) ? updv[m] : qrm[m].z;
        qo.w = (k == 3) ? updv[m] : qrm[m].w;
        ((float4*)Qn)[idx] = qo;
        prof[idx] = p_own;
    }

    // fermi: recompute selected neighbors' upd bit-identically (4 chains)
    float e2[CROWS];
    int   Bn[CROWS];
    #pragma unroll
    for (int m = 0; m < CROWS; ++m) {
        Bn[m] = tile[m + 3 + di[m]][t + 4 + dj[m]];
        float p_nb   = profit_from_b(m + 2 + di[m], t + 2 + dj[m], Bn[m]);
        float upd_nb = upd_of(p_nb, qn4[m], An[m], Bn[m]);
        float e1 = __fsub_rn(updv[m], upd_nb);
        e2[m] = __fmul_rn(e1, 2.0f);           // / K_FERMI(0.5) exactly
    }
    #pragma unroll
    for (int m = 0; m < CROWS; ++m) {
        float ex = (float)exp((double)e2[m]);  // same as passing rounds
        float W  = __fdiv_rn(1.0f, __fadd_rn(1.0f, ex));
        int sel = (pvm[m] <= W) ? Bn[m] : B[m];
        t1out[idx0 + (m << LSHIFT)] = (float)sel;
    }
}

extern "C" void kernel_launch(void* const* d_in, const int* in_sizes, int n_in,
                              void* d_out, int out_size, void* d_ws, size_t ws_size,
                              hipStream_t stream) {
    const int*   type_t_minus = (const int*)d_in[0];
    const int*   type_t       = (const int*)d_in[1];
    const float* Q_tensor     = (const float*)d_in[2];
    const int*   ldir         = (const int*)d_in[3];
    const float* lprob        = (const float*)d_in[4];

    float* out   = (float*)d_out;
    float* Qn    = out;                       // [N*4]
    float* t1out = out + (size_t)4 * NCELL;   // [N]
    float* prof  = out + (size_t)5 * NCELL;   // [N]

    const int threads = 256;
    const int blocks  = NCELL / (threads * CROWS);  // 4096 (4 rows x 256 cols)
    spgg_fused<<<blocks, threads, 0, stream>>>(type_t_minus, type_t, Q_tensor,
                                               ldir, lprob, Qn, prof, t1out);
}

// Round 4
// 212.350 us; speedup vs baseline: 1.0041x; 1.0041x over previous
//
#include <hip/hip_runtime.h>

// SPGG Q-learning step on a 2048x2048 torus — SINGLE fused kernel, v5
// ("waveflow": zero barriers).
//
// v4 post-mortem (72.6 us): every pipe <=32%; time only ever moved 1:1 with
// issue-work removed across v1->v4 -> the kernel is barrier-convoy bound.
// __syncthreads drains vmcnt/lgkm to 0 for all 4 waves together, so each
// block serializes {HBM rtt -> barrier -> LDS rtt -> barrier -> tail}.
// Also v4's deferred gathers re-missed L2 (FETCH 74.8->83.8 MB) because one
// barrier-convoy separated them from the Q[idx] loads.
//
// v5 restructures so ALL cross-lane LDS traffic stays inside one wave:
// each wave owns a private 4-row x 64-col strip (tile 10x72 int +
// btile 8x68 f32 = 5056 B/wave, 20224 B/block -> 8 blocks/CU).
//   - ZERO __syncthreads. Wave-internal visibility = s_waitcnt lgkmcnt(0)
//     + compiler memory fence (asm "memory"). No convoy: waves flow
//     independently, CU always has runnable waves.
//   - tt staging is reg-staged (3 int4 -> ds_write_b128): compiler emits
//     fine-counted vmcnt per row; the 16 per-cell loads issued first are
//     never drained at a phase edge — they retire at first use.
//   - neighbor gathers issue right after ldir arrives (counted wait), so
//     they stay temporally close to Q[idx] -> L2-hit again (undo v4's
//     FETCH regression).
//   - bval: sliding vertical window per column (26 LDS reads/col vs 40).
//
// Numerics: identical per-cell op sequence as the passing v1-v4 (int-exact
// coop sums; __f*_rn ops in the reference's exact order; exp in double,
// rounded once).

#define LSIDE 2048
#define LMASK 2047
#define LSHIFT 11
#define NCELL (LSIDE * LSIDE)

#define CROWS 4          // cell rows per wave
#define TR 10            // tt tile rows  (i0-3 .. i0+6)
#define TC 72            // tt tile cols  (j0w-4 .. j0w+67), ints
#define BR 8             // btile rows    (i0-2 .. i0+5)
#define BC 68            // btile cols    (j0w-2 .. j0w+65)
#define TILE_INTS (TR * TC)              // 720
#define BT_INTS   (BR * BC)              // 544
#define WREG      (TILE_INTS + BT_INTS)  // 1264 ints = 5056 B per wave
#define NI4       180                    // int4s staged per wave (10*18)

__global__ __launch_bounds__(256) void spgg_fused(
    const int* __restrict__ tmin,   // type_t_minus
    const int* __restrict__ tt,     // type_t
    const float* __restrict__ Q,    // Q_tensor [N,4]
    const int* __restrict__ ldir,   // learning_direction
    const float* __restrict__ lp,   // learning_probabilities
    float* __restrict__ Qn,         // out: Q_new [N,4]
    float* __restrict__ prof,       // out: profit [N]
    float* __restrict__ t1out)      // out: type_t1 [N]
{
    __shared__ __align__(16) int lds_raw[4 * WREG];   // 20224 B

    const int tid  = threadIdx.x;
    const int lane = tid & 63;
    const int wid  = tid >> 6;
    int*   wtile = lds_raw + wid * WREG;          // [TR][TC] ints
    float* wbt   = (float*)(wtile + TILE_INTS);   // [BR][BC] floats

    const int blk  = blockIdx.x;
    const int i0   = (blk >> 3) << 2;             // 4 lattice rows per block
    const int j0w  = ((blk & 7) << 8) + (wid << 6);  // this wave's 64-col window
    const int j    = j0w + lane;
    const int idx0 = (i0 << LSHIFT) + j;

    // ---- 1. per-cell loads (issued first; retire at first use, never drained) ----
    int dirm[CROWS]; float pvm[CROWS]; float4 qrm[CROWS]; int Am[CROWS];
    #pragma unroll
    for (int m = 0; m < CROWS; ++m) {
        int idx = idx0 + (m << LSHIFT);
        dirm[m] = ldir[idx];
        pvm[m]  = lp[idx];
        qrm[m]  = ((const float4*)Q)[idx];
        Am[m]   = tmin[idx];
    }

    // ---- 2. stage tt tile, reg-staged (compiler fine-counts vmcnt) ----
    {
        auto srcp = [&](int k) -> const int4* {
            int r  = k / 18;                       // tile row 0..9
            int c4 = k - r * 18;                   // int4 within row
            int row_g = (i0 + r - 3) & LMASK;
            int col_g = (j0w - 4 + (c4 << 2)) & LMASK;   // mult of 4 -> aligned
            return (const int4*)&tt[(row_g << LSHIFT) + col_g];
        };
        const int k0 = lane, k1 = 64 + lane, k2 = 128 + lane;
        int4 v0 = *srcp(k0);
        int4 v1 = *srcp(k1);
        int4 v2;
        const bool has2 = (k2 < NI4);              // lanes 0..51
        if (has2) v2 = *srcp(k2);
        *(int4*)&wtile[k0 << 2] = v0;
        *(int4*)&wtile[k1 << 2] = v1;
        if (has2) *(int4*)&wtile[k2 << 2] = v2;
    }

    // ---- 3. neighbor gathers: issue now (close to Q[idx] loads), use later ----
    int di[CROWS], dj[CROWS]; float4 qn4[CROWS]; int An[CROWS];
    #pragma unroll
    for (int m = 0; m < CROWS; ++m) {
        // dir: 0=left(j-1) 1=right(j+1) 2=up(i-1) 3=down(i+1)
        di[m] = (dirm[m] == 3) - (dirm[m] == 2);
        dj[m] = (dirm[m] == 1) - (dirm[m] == 0);
        int nidx = (((i0 + m + di[m]) & LMASK) << LSHIFT) + ((j + dj[m]) & LMASK);
        qn4[m] = ((const float4*)Q)[nidx];
        An[m]  = tmin[nidx];
    }

    // ---- 4. fence: staging ds_writes visible to all lanes of this wave ----
    asm volatile("s_waitcnt lgkmcnt(0)" ::: "memory");

    const float KB        = 0.5554f;  // float32(R / 5.0)
    const float ETA       = 0.8f;
    const float ONE_M_ETA = 0.2f;     // float32(1.0 - 0.8)
    const float GAMMA     = 0.8f;

    // ---- 5. bval: one column per lane (sliding vertical window) ----
    // btile[r][c] <-> global (i0-2+r, j0w-2+c) <-> tile (r+1, c+2).
    // tt is {0,1}: coop mask IS the value; int adds exact (order-free);
    // single __fmul_rn is the reference op.
    auto bcol = [&](int c) {
        const int tc = c + 2;
        int a[TR];
        #pragma unroll
        for (int r = 0; r < TR; ++r) a[r] = wtile[r * TC + tc];
        #pragma unroll
        for (int r = 0; r < BR; ++r) {
            int cn = a[r + 1] + a[r] + a[r + 2]
                   + wtile[(r + 1) * TC + tc - 1]
                   + wtile[(r + 1) * TC + tc + 1];
            wbt[r * BC + c] = __fmul_rn((float)cn, KB);
        }
    };
    bcol(lane);
    if (lane < BC - 64) bcol(64 + lane);   // lanes 0..3 do cols 64..67

    // ---- 6. fence: btile visible to all lanes of this wave ----
    asm volatile("s_waitcnt lgkmcnt(0)" ::: "memory");

    // profit at btile coords (r,c) — reference's exact op order:
    // plus_sum order (c, i-1, i+1, j-1, j+1); s1 subtracts 1.0 per term.
    auto profit_from_b = [&](int r, int c, int coop) -> float {
        float b_c = wbt[r * BC + c];
        float b_u = wbt[(r - 1) * BC + c];
        float b_d = wbt[(r + 1) * BC + c];
        float b_l = wbt[r * BC + c - 1];
        float b_r = wbt[r * BC + c + 1];
        float s0 = __fadd_rn(__fadd_rn(__fadd_rn(__fadd_rn(b_c, b_u), b_d), b_l), b_r);
        float s1 = __fadd_rn(__fadd_rn(__fadd_rn(__fadd_rn(
                       __fsub_rn(b_c, 1.0f), __fsub_rn(b_u, 1.0f)),
                       __fsub_rn(b_d, 1.0f)), __fsub_rn(b_l, 1.0f)),
                       __fsub_rn(b_r, 1.0f));
        return coop ? s1 : s0;
    };

    // Q-learning update value — exact reference op order.
    auto upd_of = [&](float profit, float4 q4, int Ai, int Bi) -> float {
        float q0 = (Bi == 0) ? q4.x : q4.z;
        float q1 = (Bi == 0) ? q4.y : q4.w;
        float mx = fmaxf(q0, q1);
        int k = Ai * 2 + Bi;
        float old = (k == 0) ? q4.x : ((k == 1) ? q4.y : ((k == 2) ? q4.z : q4.w));
        float t0 = __fmul_rn(GAMMA, mx);
        float t1 = __fadd_rn(profit, t0);
        float t2 = __fmul_rn(ETA, t1);
        float t3 = __fmul_rn(ONE_M_ETA, old);
        return __fadd_rn(t3, t2);
    };

    // ---- 7. own cells: profit + Q update + stores ----
    int   B[CROWS];
    float updv[CROWS];
    #pragma unroll
    for (int m = 0; m < CROWS; ++m) {
        B[m] = wtile[(m + 3) * TC + lane + 4];
        float p_own = profit_from_b(m + 2, lane + 2, B[m]);
        updv[m] = upd_of(p_own, qrm[m], Am[m], B[m]);
        int idx = idx0 + (m << LSHIFT);
        int k = Am[m] * 2 + B[m];
        float4 qo;
        qo.x = (k == 0) ? updv[m] : qrm[m].x;
        qo.y = (k == 1) ? updv[m] : qrm[m].y;
        qo.z = (k == 2) ? updv[m] : qrm[m].z;
        qo.w = (k == 3) ? updv[m] : qrm[m].w;
        ((float4*)Qn)[idx] = qo;
        prof[idx] = p_own;
    }

    // ---- 8. fermi: recompute selected neighbors' upd bit-identically ----
    float e2[CROWS];
    int   Bn[CROWS];
    #pragma unroll
    for (int m = 0; m < CROWS; ++m) {
        Bn[m] = wtile[(m + 3 + di[m]) * TC + lane + 4 + dj[m]];
        float p_nb   = profit_from_b(m + 2 + di[m], lane + 2 + dj[m], Bn[m]);
        float upd_nb = upd_of(p_nb, qn4[m], An[m], Bn[m]);
        float e1 = __fsub_rn(updv[m], upd_nb);
        e2[m] = __fmul_rn(e1, 2.0f);           // / K_FERMI(0.5) exactly
    }
    #pragma unroll
    for (int m = 0; m < CROWS; ++m) {
        float ex = (float)exp((double)e2[m]);  // same as passing rounds
        float W  = __fdiv_rn(1.0f, __fadd_rn(1.0f, ex));
        int sel = (pvm[m] <= W) ? Bn[m] : B[m];
        t1out[idx0 + (m << LSHIFT)] = (float)sel;
    }
}

extern "C" void kernel_launch(void* const* d_in, const int* in_sizes, int n_in,
                              void* d_out, int out_size, void* d_ws, size_t ws_size,
                              hipStream_t stream) {
    const int*   type_t_minus = (const int*)d_in[0];
    const int*   type_t       = (const int*)d_in[1];
    const float* Q_tensor     = (const float*)d_in[2];
    const int*   ldir         = (const int*)d_in[3];
    const float* lprob        = (const float*)d_in[4];

    float* out   = (float*)d_out;
    float* Qn    = out;                       // [N*4]
    float* t1out = out + (size_t)4 * NCELL;   // [N]
    float* prof  = out + (size_t)5 * NCELL;   // [N]

    const int threads = 256;
    const int blocks  = NCELL / (threads * CROWS);  // 4096
    spgg_fused<<<blocks, threads, 0, stream>>>(type_t_minus, type_t, Q_tensor,
                                               ldir, lprob, Qn, prof, t1out);
}